// Round 8
// baseline (152.705 us; speedup 1.0000x reference)
//
#include <hip/hip_runtime.h>
#include <hip/hip_bf16.h>
#include <stdint.h>

#define CIN   512
#define COUT  512
#define NIB   16            // 512/32 i-blocks
#define KSTEPS 128          // NIB * 8 degrees (d=1..8); d=0 folded into bias

typedef float f32x4 __attribute__((ext_vector_type(4)));
typedef short s16x8 __attribute__((ext_vector_type(8)));

// Frag-packed bf16 weights: [ks(128)][cg(32)][lane(64)] of 8 bf16 (16B)
// (verified round-2 layout) lane l holds B[k=8*(l>>4)+j][n=l&15], ks=ib*8+(d-1)
__device__ uint4 Wp_g[KSTEPS * 32 * 64];   // 4 MB
__device__ float bias_g[COUT];

__device__ __forceinline__ uint32_t cvtpk(float lo, float hi) {
  uint32_t r;
  asm("v_cvt_pk_bf16_f32 %0, %1, %2" : "=v"(r) : "v"(lo), "v"(hi));
  return r;  // low 16 = bf16(lo), high 16 = bf16(hi)
}

__device__ __forceinline__ float ftanh(float v) {
  float e = __expf(v + v);
  return 1.0f - __fdividef(2.0f, e + 1.0f);
}

// ---- pack weights into MFMA B-fragment order, bf16 (round-2 verified) ----
__global__ void pack_w(const float* __restrict__ cw) {
  __shared__ float lf[32 * 144];
  int ib = blockIdx.x >> 5;
  int cg = blockIdx.x & 31;
  for (int r = threadIdx.x; r < 32 * 144; r += 256) {
    int il = r / 144;
    int rem = r - il * 144;
    lf[r] = cw[(size_t)(ib * 32 + il) * (COUT * 9) + cg * 144 + rem];
  }
  __syncthreads();
  for (int v = threadIdx.x; v < 512; v += 256) {
    int ksl = v >> 6;            // d-1
    int lane = v & 63;
    int d = ksl + 1;
    int lh = lane >> 4, l15 = lane & 15;
    uint32_t p[4];
    #pragma unroll
    for (int q = 0; q < 4; ++q) {
      float a = lf[(lh * 8 + 2 * q    ) * 144 + l15 * 9 + d];
      float b = lf[(lh * 8 + 2 * q + 1) * 144 + l15 * 9 + d];
      p[q] = cvtpk(a, b);
    }
    Wp_g[((ib * 8 + ksl) * 32 + cg) * 64 + lane] = make_uint4(p[0], p[1], p[2], p[3]);
  }
}

// ---- bias[o] = sum_i C[i][o][0] (d=0 / T_0==1 term): one block per o ----
__global__ void bias_k(const float* __restrict__ cw) {
  int o = blockIdx.x;
  int t = threadIdx.x;
  float s = 0.f;
  #pragma unroll
  for (int q = 0; q < 8; ++q)
    s += cw[(size_t)(t + 64 * q) * (COUT * 9) + o * 9];
  #pragma unroll
  for (int off = 32; off; off >>= 1) s += __shfl_down(s, off);
  if (t == 0) bias_g[o] = s;
}

// ---- fused basis-generation + GEMM: A fully in registers ----
// 128x256 block, 8 waves (2x4 grid of 64x64 wave tiles). Each i-block is
// processed in TWO passes (row-fragments {0,1} then {2,3}): 16 Chebyshev
// chains live per pass (48 VGPR state), cvt_pk feeds MFMA A directly.
// NO LDS, NO barriers. x prefetched one pass ahead into ping-pong xbufA/B
// (pure SSA, no WAR). B prefetched 1 kstep ahead (parity regs).
__global__ void __launch_bounds__(512, 2) cheby_gemm(const float* __restrict__ x,
                                                     float* __restrict__ out) {
  const int tid  = threadIdx.x;
  const int lane = tid & 63;
  const int l15  = lane & 15;
  const int lh   = lane >> 4;
  const int w    = tid >> 6;        // 0..7
  const int wr   = w >> 2;          // 2 row-groups of 64
  const int wc   = w & 3;           // 4 col-groups of 64

  // bijective XCD swizzle (256 blocks, 256 % 8 == 0)
  int b0  = blockIdx.x;
  int bid = (b0 & 7) * 32 + (b0 >> 3);
  const int rb  = (bid >> 1) * 128;
  const int cb  = bid & 1;
  const int ocb = cb * 256;
  const int cgbase = cb * 16 + wc * 4;

  // B pointer hoist (round-2 verified addressing)
  const uint4* pB = Wp_g + (size_t)cgbase * 64 + lane;

  // x base for this lane's fragment rows: row(rf) = rb + wr*64 + rf*16 + l15,
  // i-chunk lh*8 (A slot (l,e) holds T[row][i = ib*32 + 8*lh + e])
  const float* xbase = x + (size_t)(rb + wr * 64 + l15) * CIN + lh * 8;

  // accumulators, initialized with the d=0 bias term (round-2 verified)
  f32x4 acc[4][4];
  #pragma unroll
  for (int cf = 0; cf < 4; ++cf) {
    float bv = bias_g[ocb + wc * 64 + cf * 16 + l15];
    #pragma unroll
    for (int rf = 0; rf < 4; ++rf) {
      acc[rf][cf][0] = bv; acc[rf][cf][1] = bv;
      acc[rf][cf][2] = bv; acc[rf][cf][3] = bv;
    }
  }

  // per-pass chain state (16 chains: 2 rows x 8 i) + ping-pong x prefetch
  float xbufA[16], xbufB[16];
  float u2[16], tm1[16], tm2[16];

  auto prefetch_to = [&](float* dst, int qq) {   // pass qq = ib*2 + p
    int ibq = qq >> 1, pq = qq & 1;
    #pragma unroll
    for (int rl = 0; rl < 2; ++rl) {
      const float4* p4 = reinterpret_cast<const float4*>(
          xbase + (size_t)(pq * 2 + rl) * 16 * CIN + ibq * 32);
      float4 a = p4[0], b = p4[1];
      dst[rl*8+0]=a.x; dst[rl*8+1]=a.y; dst[rl*8+2]=a.z; dst[rl*8+3]=a.w;
      dst[rl*8+4]=b.x; dst[rl*8+5]=b.y; dst[rl*8+6]=b.z; dst[rl*8+7]=b.w;
    }
  };
  auto compute_u = [&](const float* src) {
    #pragma unroll
    for (int c = 0; c < 16; ++c) {
      float u = ftanh(ftanh(src[c]));
      tm1[c] = u; tm2[c] = 1.0f; u2[c] = u + u;
    }
  };
  auto advance = [&]() {
    #pragma unroll
    for (int c = 0; c < 16; ++c) {
      float t = __builtin_fmaf(u2[c], tm1[c], -tm2[c]);
      tm2[c] = tm1[c]; tm1[c] = t;
    }
  };

  s16x8 breg[2][4];                 // [parity][cf]
  auto loadB = [&](int par, int ks) {
    #pragma unroll
    for (int cf = 0; cf < 4; ++cf) {
      uint4 v = pB[(size_t)ks * 2048 + cf * 64];
      breg[par][cf] = __builtin_bit_cast(s16x8, v);
    }
  };

  // ---- prologue ----
  prefetch_to(xbufA, 0);
  loadB(0, 0);

  for (int ib = 0; ib < NIB; ++ib) {
    #pragma unroll
    for (int p = 0; p < 2; ++p) {
      // pass q = ib*2 + p; since 2*ib is even, q&1 == p (static buffers)
      const float* src = p ? xbufB : xbufA;
      float*       nxt = p ? xbufA : xbufB;
      compute_u(src);                          // chains for rows {2p, 2p+1}
      if (!(ib == NIB - 1 && p == 1))
        prefetch_to(nxt, ib * 2 + p + 1);      // consumed one pass later
      #pragma unroll
      for (int j = 0; j < 8; ++j) {            // degree d = j+1
        int ks = ib * 8 + j;
        int nks = (j < 7) ? ks + 1 : ((p == 0) ? ib * 8 : (ib + 1) * 8);
        if (!(ib == NIB - 1 && p == 1 && j == 7)) loadB((j + 1) & 1, nks);
        if (j > 0) advance();                  // tm1 = T_{j+1}
        __builtin_amdgcn_s_setprio(1);
        #pragma unroll
        for (int rl = 0; rl < 2; ++rl) {
          uint32_t q0 = cvtpk(tm1[rl*8+0], tm1[rl*8+1]);
          uint32_t q1 = cvtpk(tm1[rl*8+2], tm1[rl*8+3]);
          uint32_t q2 = cvtpk(tm1[rl*8+4], tm1[rl*8+5]);
          uint32_t q3 = cvtpk(tm1[rl*8+6], tm1[rl*8+7]);
          s16x8 af = __builtin_bit_cast(s16x8, make_uint4(q0, q1, q2, q3));
          #pragma unroll
          for (int cf = 0; cf < 4; ++cf)
            acc[p * 2 + rl][cf] = __builtin_amdgcn_mfma_f32_16x16x32_bf16(
                af, breg[j & 1][cf], acc[p * 2 + rl][cf], 0, 0, 0);
        }
        __builtin_amdgcn_s_setprio(0);
      }
    }
  }

  // ---- epilogue: C/D layout col = lane&15, row = (lane>>4)*4 + reg ----
  const int orow = rb + wr * 64 + lh * 4;
  const int ocol = ocb + wc * 64 + l15;
  #pragma unroll
  for (int rf = 0; rf < 4; ++rf) {
    #pragma unroll
    for (int cf = 0; cf < 4; ++cf) {
      #pragma unroll
      for (int r = 0; r < 4; ++r)
        out[(size_t)(orow + rf * 16 + r) * COUT + ocol + cf * 16] = acc[rf][cf][r];
    }
  }
}

extern "C" void kernel_launch(void* const* d_in, const int* in_sizes, int n_in,
                              void* d_out, int out_size, void* d_ws, size_t ws_size,
                              hipStream_t stream) {
  const float* x  = (const float*)d_in[0];   // (16384, 512) fp32
  const float* cw = (const float*)d_in[1];   // (512, 512, 9) fp32
  float* out = (float*)d_out;                // (16384, 512) fp32

  pack_w<<<dim3(512), dim3(256), 0, stream>>>(cw);
  bias_k<<<dim3(COUT), dim3(64), 0, stream>>>(cw);
  cheby_gemm<<<dim3(256), dim3(512), 0, stream>>>(x, out);
}

// Round 9
// 101.173 us; speedup vs baseline: 1.5094x; 1.5094x over previous
//
#include <hip/hip_runtime.h>
#include <hip/hip_bf16.h>
#include <stdint.h>

#define CIN   512
#define COUT  512
#define BM    128
#define BN    256
#define NIB   16            // 512/32 i-blocks
#define KSTEPS 128          // NIB * 8 degrees (d=1..8); d=0 folded into bias

typedef float f32x4 __attribute__((ext_vector_type(4)));
typedef short s16x8 __attribute__((ext_vector_type(8)));

// Frag-packed bf16 weights: [ks(128)][cg(32)][lane(64)] of 8 bf16 (16B)
__device__ uint4 Wp_g[KSTEPS * 32 * 64];   // 4 MB
__device__ float bias_g[COUT];

__device__ __forceinline__ uint32_t cvtpk(float lo, float hi) {
  uint32_t r;
  asm("v_cvt_pk_bf16_f32 %0, %1, %2" : "=v"(r) : "v"(lo), "v"(hi));
  return r;  // low 16 = bf16(lo), high 16 = bf16(hi)
}

__device__ __forceinline__ float ftanh(float v) {
  float e = __expf(v + v);
  return 1.0f - __fdividef(2.0f, e + 1.0f);
}

// ---- pack weights into MFMA B-fragment order, bf16 (round-2 verified) ----
__global__ void pack_w(const float* __restrict__ cw) {
  __shared__ float lf[32 * 144];
  int ib = blockIdx.x >> 5;
  int cg = blockIdx.x & 31;
  for (int r = threadIdx.x; r < 32 * 144; r += 256) {
    int il = r / 144;
    int rem = r - il * 144;
    lf[r] = cw[(size_t)(ib * 32 + il) * (COUT * 9) + cg * 144 + rem];
  }
  __syncthreads();
  for (int v = threadIdx.x; v < 512; v += 256) {
    int ksl = v >> 6;            // d-1
    int lane = v & 63;
    int d = ksl + 1;
    int lh = lane >> 4, l15 = lane & 15;
    uint32_t p[4];
    #pragma unroll
    for (int q = 0; q < 4; ++q) {
      float a = lf[(lh * 8 + 2 * q    ) * 144 + l15 * 9 + d];
      float b = lf[(lh * 8 + 2 * q + 1) * 144 + l15 * 9 + d];
      p[q] = cvtpk(a, b);
    }
    Wp_g[((ib * 8 + ksl) * 32 + cg) * 64 + lane] = make_uint4(p[0], p[1], p[2], p[3]);
  }
}

// ---- bias[o] = sum_i C[i][o][0] (d=0 / T_0==1 term): one block per o ----
__global__ void bias_k(const float* __restrict__ cw) {
  int o = blockIdx.x;
  int t = threadIdx.x;
  float s = 0.f;
  #pragma unroll
  for (int q = 0; q < 8; ++q)
    s += cw[(size_t)(t + 64 * q) * (COUT * 9) + o * 9];
  #pragma unroll
  for (int off = 32; off; off >>= 1) s += __shfl_down(s, off);
  if (t == 0) bias_g[o] = s;
}

// ---- fused basis-generation + GEMM, m201-style per-phase discipline ----
// 128x256 tile, 8 waves (2x4 grid of 64x64), grid=256. Per phase (=kstep):
// window { ds_read A(next) | loadB(next) | gen advance/emit } ->
// lgkmcnt(0)+sched_barrier -> s_barrier -> setprio(1) 16 MFMA setprio(0)
// -> s_barrier.  B prefetch stays in flight across barriers (no vmcnt drain).
// Emit->read distance >= 3 barriers for every slot (verified).
__global__ void __launch_bounds__(512, 1) cheby_gemm(const float* __restrict__ x,
                                                     float* __restrict__ out) {
  __shared__ uint4 lds[2 * 4 * 4 * BM];   // [buf][slot(4 d)][h(4)][row(128)] = 64 KB
  const int tid  = threadIdx.x;
  const int lane = tid & 63;
  const int l15  = lane & 15;
  const int lh   = lane >> 4;
  const int w    = tid >> 6;
  const int wr   = w >> 2;          // 2 row-groups of 64
  const int wc   = w & 3;           // 4 col-groups of 64

  // bijective XCD swizzle (256 blocks, 256 % 8 == 0)
  int b0  = blockIdx.x;
  int bid = (b0 & 7) * 32 + (b0 >> 3);
  const int rb  = (bid >> 1) * BM;
  const int cb  = bid & 1;
  const int ocb = cb * BN;
  const int cgbase = cb * 16 + wc * 4;

  // generator mapping: wave-contiguous LDS writes, 8 elems/thread
  const int ge   = w >> 1;                 // i-chunk of 8 (0..3)
  const int grow = (w & 1) * 64 + lane;    // row (0..127)
  const float* xrow = x + (size_t)(rb + grow) * CIN + ge * 8;

  const uint4* pB = Wp_g + (size_t)cgbase * 64 + lane;

  // accumulators, initialized with the d=0 bias term
  f32x4 acc[4][4];
  #pragma unroll
  for (int cf = 0; cf < 4; ++cf) {
    float bv = bias_g[ocb + wc * 64 + cf * 16 + l15];
    #pragma unroll
    for (int rf = 0; rf < 4; ++rf) {
      acc[rf][cf][0] = bv; acc[rf][cf][1] = bv;
      acc[rf][cf][2] = bv; acc[rf][cf][3] = bv;
    }
  }

  float xv[8], u2[8], tm1[8], tm2[8];

  auto loadX = [&](int ib) {
    const float4* p = reinterpret_cast<const float4*>(xrow + ib * 32);
    float4 v0 = p[0], v1 = p[1];
    xv[0] = v0.x; xv[1] = v0.y; xv[2] = v0.z; xv[3] = v0.w;
    xv[4] = v1.x; xv[5] = v1.y; xv[6] = v1.z; xv[7] = v1.w;
  };
  auto compute_u = [&]() {
    #pragma unroll
    for (int k = 0; k < 8; ++k) {
      float u = ftanh(ftanh(xv[k]));
      tm1[k] = u; tm2[k] = 1.0f; u2[k] = u + u;
    }
  };
  auto advance = [&]() {
    #pragma unroll
    for (int k = 0; k < 8; ++k) {
      float t = __builtin_fmaf(u2[k], tm1[k], -tm2[k]);
      tm2[k] = tm1[k]; tm1[k] = t;
    }
  };
  auto emit = [&](int buf, int slot) {   // write current tm1[] (= T_d) as bf16
    uint32_t p0 = cvtpk(tm1[0], tm1[1]);
    uint32_t p1 = cvtpk(tm1[2], tm1[3]);
    uint32_t p2 = cvtpk(tm1[4], tm1[5]);
    uint32_t p3 = cvtpk(tm1[6], tm1[7]);
    lds[((buf * 4 + slot) * 4 + ge) * BM + grow] = make_uint4(p0, p1, p2, p3);
  };

  s16x8 aA[4], aB[4];               // ping-pong A fragments
  s16x8 breg[2][4];                 // [parity][cf]
  auto loadB = [&](int par, int ks) {
    #pragma unroll
    for (int cf = 0; cf < 4; ++cf) {
      uint4 v = pB[(size_t)ks * 2048 + cf * 64];
      breg[par][cf] = __builtin_bit_cast(s16x8, v);
    }
  };
  auto dsreadA = [&](s16x8 (&dst)[4], int buf, int slot) {
    int base = ((buf * 4 + slot) * 4 + lh) * BM + wr * 64 + l15;
    #pragma unroll
    for (int rf = 0; rf < 4; ++rf)
      dst[rf] = *reinterpret_cast<const s16x8*>(&lds[base + rf * 16]);
  };
  auto barrier_pre = [&]() {
    asm volatile("s_waitcnt lgkmcnt(0)" ::: "memory");
    __builtin_amdgcn_sched_barrier(0);
    __builtin_amdgcn_s_barrier();
  };
  auto mfma16 = [&](s16x8 (&a)[4], int par) {
    __builtin_amdgcn_s_setprio(1);
    #pragma unroll
    for (int rf = 0; rf < 4; ++rf) {
      #pragma unroll
      for (int cf = 0; cf < 4; ++cf)
        acc[rf][cf] = __builtin_amdgcn_mfma_f32_16x16x32_bf16(
            a[rf], breg[par][cf], acc[rf][cf], 0, 0, 0);
    }
    __builtin_amdgcn_s_setprio(0);
    __builtin_amdgcn_s_barrier();
  };

  // ---- prologue: generate (ib=0, d=1..4) into buf0; preload a(0,0) ----
  loadX(0);
  compute_u();
  emit(0, 0);                 // d=1 : T_1 = u
  advance(); emit(0, 1);      // d=2
  advance(); emit(0, 2);      // d=3
  advance(); emit(0, 3);      // d=4
  loadB(0, 0);
  barrier_pre();              // emits drained, all waves synced
  dsreadA(aA, 0, 0);          // a_cur for phase 0 (drained at phase-0 barrier)

  for (int ib = 0; ib < NIB; ++ib) {
    if (ib + 1 < NIB) loadX(ib + 1);   // consumed at PART1 j=0 (compute_u)

    // PART 0: phases j=0..3 consume buf0 slot j; gen (ib, d=5..8) -> buf1
    #pragma unroll
    for (int j = 0; j < 4; ++j) {
      int ks = ib * 8 + j;
      // pre-barrier window:
      if (j < 3) { if (j & 1) dsreadA(aA, 0, j + 1); else dsreadA(aB, 0, j + 1); }
      else       dsreadA(aA, 1, 0);      // j==3 (odd): next into aA
      loadB((j + 1) & 1, ks + 1);        // ks+1 <= 124 always here
      advance(); emit(1, j);             // d = 5+j
      barrier_pre();
      if (j & 1) mfma16(aB, 1); else mfma16(aA, 0);
    }

    // PART 1: phases j=0..3 consume buf1 slot j; gen (ib+1, d=1..4) -> buf0
    #pragma unroll
    for (int j = 0; j < 4; ++j) {
      int ks = ib * 8 + 4 + j;
      if (j < 3) { if (j & 1) dsreadA(aA, 1, j + 1); else dsreadA(aB, 1, j + 1); }
      else if (ib + 1 < NIB) dsreadA(aA, 0, 0);   // next ib's first slot
      if (ks + 1 < KSTEPS) loadB((j + 1) & 1, ks + 1);
      if (ib + 1 < NIB) {
        if (j == 0) { compute_u(); emit(0, 0); }
        else        { advance();   emit(0, j); }
      }
      barrier_pre();
      if (j & 1) mfma16(aB, 1); else mfma16(aA, 0);
    }
  }

  // ---- epilogue: C/D layout col = lane&15, row = (lane>>4)*4 + reg ----
  const int orow = rb + wr * 64 + lh * 4;
  const int ocol = ocb + wc * 64 + l15;
  #pragma unroll
  for (int rf = 0; rf < 4; ++rf) {
    #pragma unroll
    for (int cf = 0; cf < 4; ++cf) {
      #pragma unroll
      for (int r = 0; r < 4; ++r)
        out[(size_t)(orow + rf * 16 + r) * COUT + ocol + cf * 16] = acc[rf][cf][r];
    }
  }
}

extern "C" void kernel_launch(void* const* d_in, const int* in_sizes, int n_in,
                              void* d_out, int out_size, void* d_ws, size_t ws_size,
                              hipStream_t stream) {
  const float* x  = (const float*)d_in[0];   // (16384, 512) fp32
  const float* cw = (const float*)d_in[1];   // (512, 512, 9) fp32
  float* out = (float*)d_out;                // (16384, 512) fp32

  pack_w<<<dim3(512), dim3(256), 0, stream>>>(cw);
  bias_k<<<dim3(COUT), dim3(64), 0, stream>>>(cw);
  cheby_gemm<<<dim3(256), dim3(512), 0, stream>>>(x, out);
}